// Round 10
// baseline (313.644 us; speedup 1.0000x reference)
//
#include <hip/hip_runtime.h>
#include <hip/hip_fp16.h>

#define EPSBN 2e-5f

typedef _Float16 hf2 __attribute__((ext_vector_type(2)));

static __device__ __forceinline__ float fdot2h(hf2 a, hf2 b, float c) {
  return __builtin_amdgcn_fdot2(a, b, c, false);
}
static __device__ __forceinline__ unsigned pk(float a, float b) {
  union { __half2 h; unsigned u; } u;
  u.h = __floats2half2_rn(a, b);
  return u.u;
}
static __device__ __forceinline__ float2 uph(unsigned v) {
  union { unsigned u; __half2 h; } x; x.u = v;
  return __half22float2(x.h);
}

// ============================ Stage 1: lift (+ folded weight prep) ============
// 512 threads: sg0 waves do si{0,1,2,8}, sg1 waves do si{3,4,5,6,7}.
#define NB1 4
template<int SI>
__device__ __forceinline__ void s1_si(const unsigned* __restrict__ xsu, int bb, int t0,
    const unsigned* __restrict__ wlu, int o0, bool act, int b,
    __half* __restrict__ r1, float& ts0, float& tq0, float& ts1, float& tq1) {
  constexpr int S = 1 << SI;
  float a0[10], a1[10];
#pragma unroll
  for (int k = 0; k < 10; ++k) { a0[k] = 0.f; a1[k] = 0.f; }
#pragma unroll 1
  for (int cp = 0; cp < 3; ++cp) {
    const hf2* xr = (const hf2*)xsu + (bb * 3 + cp) * 295 + 96 + t0;
    const unsigned* wp = wlu + cp * 84;
#pragma unroll
    for (int j = 0; j < 7; ++j) {
      const int off = S * (j - 3);
      if (off < -96 || off > 98) continue;
      hf2 w0 = *(const hf2*)(wp + j * 12 + o0);
      hf2 w1 = *(const hf2*)(wp + j * 12 + o0 + 1);
      hf2 xv[10];
#pragma unroll
      for (int k = 0; k < 10; ++k) xv[k] = xr[off + k];
#pragma unroll
      for (int k = 0; k < 10; ++k) {
        a0[k] = fdot2h(xv[k], w0, a0[k]);
        a1[k] = fdot2h(xv[k], w1, a1[k]);
      }
    }
  }
  if (act) {
    const float inv = 1.0f / (float)S;
    size_t rb = ((size_t)b * 12 + o0) * 9 + SI;
#pragma unroll
    for (int u = 0; u < 5; ++u) {
      float v0 = fmaxf(fmaxf(a0[2 * u], a0[2 * u + 1]) * inv, 0.f);
      float v1 = fmaxf(fmaxf(a1[2 * u], a1[2 * u + 1]) * inv, 0.f);
      r1[rb * 50 + (t0 >> 1) + u] = __float2half_rn(v0);
      r1[(rb + 9) * 50 + (t0 >> 1) + u] = __float2half_rn(v1);
      ts0 += v0; tq0 += v0 * v0; ts1 += v1; tq1 += v1 * v1;
    }
  }
}

__global__ __launch_bounds__(512) void k_lift(const float* __restrict__ x,
    const float* __restrict__ w1, const float* __restrict__ w2,
    const float* __restrict__ w3, const float* __restrict__ w4,
    __half* __restrict__ W2P, __half* __restrict__ W3P, __half* __restrict__ W4P,
    __half* __restrict__ r1, float* __restrict__ sum, float* __restrict__ sq) {
  __shared__ __align__(16) unsigned xsu[NB1 * 885];
  __shared__ __align__(16) unsigned wlu[252];
  __shared__ float ssum[12], ssq[12];
  int b0 = blockIdx.x * NB1, tid = threadIdx.x;
  {
    int gi = blockIdx.x * 512 + tid;
    if (gi < 4320) {
      int ci = gi & 1, r = gi >> 1, o = r % 24, j = (r / 24) % 5, h = (r / 120) % 3, cp = r / 360;
      int c = 2 * cp + ci;
      W2P[gi] = __float2half_rn(w2[((o * 12 + c) * 3 + h) * 5 + j]);
    } else if (gi < 21600) {
      int k = gi - 4320;
      int ci = k & 1, r = k >> 1, o = r % 48, j = (r / 48) % 5, h = (r / 240) % 3, cp = r / 720;
      int c = 2 * cp + ci;
      W3P[k] = __float2half_rn(w3[((o * 24 + c) * 3 + h) * 5 + j]);
    } else if (gi < 63072) {
      int k = gi - 21600;
      int ci = k & 1, r = k >> 1, o48 = r % 48, j = (r / 48) % 3, h = (r / 144) % 3;
      int cp = (r / 432) % 24, ch = r / 10368, c = 2 * cp + ci, o = ch * 48 + o48;
      W4P[k] = __float2half_rn(w4[((o * 48 + c) * 3 + h) * 3 + j]);
    }
  }
  for (int i = tid; i < NB1 * 885; i += 512) xsu[i] = 0u;
  for (int i = tid; i < 252; i += 512) {
    int cp = i / 84, j = (i % 84) / 12, o = i % 12;
    wlu[i] = pk(w1[(o * 6 + 2 * cp) * 7 + j], w1[(o * 6 + 2 * cp + 1) * 7 + j]);
  }
  if (tid < 12) { ssum[tid] = 0.f; ssq[tid] = 0.f; }
  __syncthreads();
  __half* xsh = (__half*)xsu;
  for (int i = tid; i < NB1 * 600; i += 512) {
    int bb = i / 600, f = i % 600, t = f / 6, c = f % 6;
    xsh[((bb * 3 + (c >> 1)) * 295 + 96 + t) * 2 + (c & 1)] =
        __float2half_rn(x[(size_t)(b0 + bb) * 600 + f]);
  }
  __syncthreads();
  int sg = tid >> 8;           // 0/1 scale group (wave-uniform)
  int t8 = tid & 255;
  bool act = t8 < 240;
  int task = act ? t8 : 0;
  int bb = task / 60, r = task % 60;
  int op = r / 10, tc = r % 10;
  int o0 = op * 2, t0 = tc * 10;
  int b = b0 + bb;
  float ts0 = 0.f, tq0 = 0.f, ts1 = 0.f, tq1 = 0.f;
  if (sg == 0) {
    s1_si<0>(xsu, bb, t0, wlu, o0, act, b, r1, ts0, tq0, ts1, tq1);
    s1_si<1>(xsu, bb, t0, wlu, o0, act, b, r1, ts0, tq0, ts1, tq1);
    s1_si<2>(xsu, bb, t0, wlu, o0, act, b, r1, ts0, tq0, ts1, tq1);
    s1_si<8>(xsu, bb, t0, wlu, o0, act, b, r1, ts0, tq0, ts1, tq1);
  } else {
    s1_si<3>(xsu, bb, t0, wlu, o0, act, b, r1, ts0, tq0, ts1, tq1);
    s1_si<4>(xsu, bb, t0, wlu, o0, act, b, r1, ts0, tq0, ts1, tq1);
    s1_si<5>(xsu, bb, t0, wlu, o0, act, b, r1, ts0, tq0, ts1, tq1);
    s1_si<6>(xsu, bb, t0, wlu, o0, act, b, r1, ts0, tq0, ts1, tq1);
    s1_si<7>(xsu, bb, t0, wlu, o0, act, b, r1, ts0, tq0, ts1, tq1);
  }
  if (act) {
    atomicAdd(&ssum[o0], ts0); atomicAdd(&ssq[o0], tq0);
    atomicAdd(&ssum[o0 + 1], ts1); atomicAdd(&ssq[o0 + 1], tq1);
  }
  __syncthreads();
  if (tid < 12) { atomicAdd(&sum[tid], ssum[tid]); atomicAdd(&sq[tid], ssq[tid]); }
}

// ============================ Stage 2 ============================
// 512 threads: 4 i2-wave-groups x (kh2 lane-pair K-split: cp 0-2 / 3-5).
// Reduction via __shfl_xor(.,1); kh0 lanes write pooled outputs + stats.
#define NB2 5
template<int S, int I2>
__device__ __forceinline__ void s2_do(const unsigned* __restrict__ abu,
    const unsigned* __restrict__ wlu, int op, int cp0, int kh, bool act, int b,
    unsigned* __restrict__ r2p, float& ts0, float& tq0, float& ts1, float& tq1) {
  float acc0[24], acc1[24];
#pragma unroll
  for (int t = 0; t < 24; ++t) { acc0[t] = 0.f; acc1[t] = 0.f; }
#pragma unroll 1
  for (int cp = cp0; cp < cp0 + 3; ++cp) {
#pragma unroll
    for (int h = 0; h < 3; ++h) {
      const hf2* ar = (const hf2*)(abu + (cp * 9 + I2 + h) * 26);
      hf2 rr[25];
#pragma unroll
      for (int t = 0; t < 25; ++t) rr[t] = ar[t];
      const unsigned* wp = wlu + ((cp * 3 + h) * 5) * 24 + op * 2;
#pragma unroll
      for (int j = 0; j < 5; ++j) {
        const int off = S * (j - 2);
        if (off <= -25 || off >= 25) continue;
        hf2 w0 = *(const hf2*)(wp + j * 24);
        hf2 w1 = *(const hf2*)(wp + j * 24 + 1);
#pragma unroll
        for (int t = 0; t < 24; ++t) {
          if (t + off >= 0 && t + off < 25) {
            acc0[t] = fdot2h(rr[t + off], w0, acc0[t]);
            acc1[t] = fdot2h(rr[t + off], w1, acc1[t]);
          }
        }
      }
    }
  }
  if (act) {
#pragma unroll
    for (int t = 0; t < 24; ++t) {
      acc0[t] += __shfl_xor(acc0[t], 1);
      acc1[t] += __shfl_xor(acc1[t], 1);
    }
    if (kh == 0) {
      const float inv = 1.0f / (float)S;
      unsigned* pd = r2p + ((size_t)b * 12 + op) * 42 + I2 * 6;
      float m0 = 0.f, m1 = 0.f;
#pragma unroll
      for (int u = 0; u < 12; ++u) {
        float v0 = fmaxf(fmaxf(acc0[2 * u], acc0[2 * u + 1]) * inv, 0.f);
        float v1 = fmaxf(fmaxf(acc1[2 * u], acc1[2 * u + 1]) * inv, 0.f);
        ts0 += v0; tq0 += v0 * v0; ts1 += v1; tq1 += v1 * v1;
        if ((u & 1) == 0) { m0 = v0; m1 = v1; }
        else pd[u >> 1] = pk(fmaxf(m0, v0), fmaxf(m1, v1));
      }
    }
  }
}

__global__ __launch_bounds__(512) void k_stage2(const __half* __restrict__ r1,
    const __half* __restrict__ W2P,
    const float* __restrict__ SUM, const float* __restrict__ SQ,
    const float* __restrict__ g, const float* __restrict__ bbn, float invN,
    unsigned* __restrict__ r2p, float* __restrict__ sum, float* __restrict__ sq, int B) {
  __shared__ __align__(16) unsigned asu[NB2 * 1405];
  __shared__ __align__(16) unsigned wlu[2160];
  __shared__ float ssum[24], ssq[24];
  __shared__ float scf[12], shf[12];
  int b0 = blockIdx.x * NB2, tid = threadIdx.x;
  if (tid < 12) {
    float m = SUM[tid] * invN;
    float v = SQ[tid] * invN - m * m;
    float scale = g[tid] * rsqrtf(v + EPSBN);
    scf[tid] = scale; shf[tid] = bbn[tid] - m * scale;
    ssum[tid] = 0.f; ssq[tid] = 0.f;
    ssum[tid + 12] = 0.f; ssq[tid + 12] = 0.f;
  }
  __syncthreads();
  for (int i = tid; i < NB2 * 1350; i += 512) {
    int bb = i / 1350, s = i % 1350;
    if (b0 + bb < B) {
      int cp = s / 225, rem = s % 225, row = rem / 25, t = rem % 25;
      int c0 = 2 * cp, c1 = c0 + 1;
      float2 a0 = __half22float2(*(const __half2*)(r1 +
          (((size_t)(b0 + bb) * 12 + c0) * 9 + row) * 50 + 2 * t));
      float2 a1 = __half22float2(*(const __half2*)(r1 +
          (((size_t)(b0 + bb) * 12 + c1) * 9 + row) * 50 + 2 * t));
      float v0 = fmaxf(a0.x, a0.y) * scf[c0] + shf[c0];
      float v1 = fmaxf(a1.x, a1.y) * scf[c1] + shf[c1];
      asu[bb * 1405 + (cp * 9 + row) * 26 + t] = pk(v0, v1);
    }
  }
  for (int i = tid; i < 540; i += 512)
    ((uint4*)wlu)[i] = ((const uint4*)W2P)[i];
  __syncthreads();
  int wv = tid >> 6, lane = tid & 63;
  int ig = wv >> 1;
  int kh = lane & 1;
  int p = ((wv & 1) << 5) + (lane >> 1);
  bool act = p < 60;
  int bb = act ? p / 12 : 4;
  int op = act ? p % 12 : 0;
  act = act && (b0 + bb < B);
  int cp0 = kh * 3;
  const unsigned* abu = asu + bb * 1405;
  int b = b0 + bb;
  float ts0 = 0.f, tq0 = 0.f, ts1 = 0.f, tq1 = 0.f;
  if (ig == 0) {
    s2_do<1, 0>(abu, wlu, op, cp0, kh, act, b, r2p, ts0, tq0, ts1, tq1);
  } else if (ig == 1) {
    s2_do<2, 1>(abu, wlu, op, cp0, kh, act, b, r2p, ts0, tq0, ts1, tq1);
    s2_do<64, 6>(abu, wlu, op, cp0, kh, act, b, r2p, ts0, tq0, ts1, tq1);
  } else if (ig == 2) {
    s2_do<4, 2>(abu, wlu, op, cp0, kh, act, b, r2p, ts0, tq0, ts1, tq1);
    s2_do<32, 5>(abu, wlu, op, cp0, kh, act, b, r2p, ts0, tq0, ts1, tq1);
  } else {
    s2_do<8, 3>(abu, wlu, op, cp0, kh, act, b, r2p, ts0, tq0, ts1, tq1);
    s2_do<16, 4>(abu, wlu, op, cp0, kh, act, b, r2p, ts0, tq0, ts1, tq1);
  }
  if (act && kh == 0) {
    int o0 = op * 2;
    atomicAdd(&ssum[o0], ts0); atomicAdd(&ssq[o0], tq0);
    atomicAdd(&ssum[o0 + 1], ts1); atomicAdd(&ssq[o0 + 1], tq1);
  }
  __syncthreads();
  if (tid < 24) { atomicAdd(&sum[tid], ssum[tid]); atomicAdd(&sq[tid], ssq[tid]); }
}

// ============================ Stage 3 ============================
// 384 threads: (bb8, op24, kh2 lane-pairs: cp 0-5 / 6-11), shfl reduction.
#define NB3 8
template<int I2>
__device__ __forceinline__ void s3h(const hf2* __restrict__ rr, int h,
    const hf2* __restrict__ w0, const hf2* __restrict__ w1, float* __restrict__ acc) {
  constexpr int S = 1 << I2;
  const int base = (I2 + h) * 6;
#pragma unroll
  for (int j = 0; j < 5; ++j) {
    const int off = S * (j - 2);
    if (off <= -6 || off >= 6) continue;
#pragma unroll
    for (int t = 0; t < 6; ++t) {
      if (t + off >= 0 && t + off < 6) {
        acc[t] = fdot2h(rr[base + t + off], w0[j], acc[t]);
        acc[6 + t] = fdot2h(rr[base + t + off], w1[j], acc[6 + t]);
      }
    }
  }
}

__global__ __launch_bounds__(384) void k_stage3(const unsigned* __restrict__ r2p,
    const __half* __restrict__ W3P,
    const float* __restrict__ SUM, const float* __restrict__ SQ,
    const float* __restrict__ g, const float* __restrict__ bbn, float invN,
    unsigned* __restrict__ r3, float* __restrict__ sum, float* __restrict__ sq) {
  __shared__ __align__(16) unsigned asu[NB3 * 505];
  __shared__ __align__(16) unsigned wlu[8640];
  __shared__ float ssum[48], ssq[48];
  __shared__ float scf[24], shf[24];
  int b0 = blockIdx.x * NB3, tid = threadIdx.x;
  if (tid < 24) {
    float m = SUM[tid] * invN;
    float v = SQ[tid] * invN - m * m;
    float scale = g[tid] * rsqrtf(v + EPSBN);
    scf[tid] = scale; shf[tid] = bbn[tid] - m * scale;
  }
  if (tid < 48) { ssum[tid] = 0.f; ssq[tid] = 0.f; }
  __syncthreads();
  for (int i = tid; i < NB3 * 504; i += 384) {
    int bb = i / 504, f = i % 504, cp = f / 42;
    int c0 = 2 * cp, c1 = c0 + 1;
    float2 a = uph(r2p[(size_t)(b0 + bb) * 504 + f]);
    asu[bb * 505 + f] = pk(a.x * scf[c0] + shf[c0], a.y * scf[c1] + shf[c1]);
  }
  for (int i = tid; i < 2160; i += 384)
    ((uint4*)wlu)[i] = ((const uint4*)W3P)[i];
  __syncthreads();
  int wv = tid >> 6, lane = tid & 63;
  int kh = lane & 1;
  int w = wv * 32 + (lane >> 1);   // 0..191
  int bb = w / 24, op = w % 24;
  int b = b0 + bb;
  float acc[60];
#pragma unroll
  for (int k = 0; k < 60; ++k) acc[k] = 0.f;
  int cp0 = kh * 6;
#pragma unroll 1
  for (int cp = cp0; cp < cp0 + 6; ++cp) {
    const hf2* ar = (const hf2*)(asu + bb * 505 + cp * 42);
    hf2 rr[42];
#pragma unroll
    for (int k = 0; k < 42; ++k) rr[k] = ar[k];
#pragma unroll
    for (int h = 0; h < 3; ++h) {
      const unsigned* wp = wlu + (cp * 15 + h * 5) * 48 + op * 2;
      hf2 w0[5], w1[5];
#pragma unroll
      for (int j = 0; j < 5; ++j) {
        w0[j] = *(const hf2*)(wp + j * 48);
        w1[j] = *(const hf2*)(wp + j * 48 + 1);
      }
      s3h<0>(rr, h, w0, w1, acc);
      s3h<1>(rr, h, w0, w1, acc + 12);
      s3h<2>(rr, h, w0, w1, acc + 24);
      s3h<3>(rr, h, w0, w1, acc + 36);
      s3h<4>(rr, h, w0, w1, acc + 48);
    }
  }
#pragma unroll
  for (int k = 0; k < 60; ++k) acc[k] += __shfl_xor(acc[k], 1);
  if (kh == 0) {
    float ts0 = 0.f, tq0 = 0.f, ts1 = 0.f, tq1 = 0.f;
    int ob = op * 2;
#pragma unroll
    for (int i2 = 0; i2 < 5; ++i2) {
      const float inv = 1.0f / (float)(1 << i2);
      size_t rb = ((size_t)b * 24 + op) * 15 + i2 * 3;
#pragma unroll
      for (int u = 0; u < 3; ++u) {
        float v0 = fmaxf(fmaxf(acc[i2 * 12 + 2 * u], acc[i2 * 12 + 2 * u + 1]) * inv, 0.f);
        float v1 = fmaxf(fmaxf(acc[i2 * 12 + 6 + 2 * u], acc[i2 * 12 + 7 + 2 * u]) * inv, 0.f);
        r3[rb + u] = pk(v0, v1);
        ts0 += v0; tq0 += v0 * v0; ts1 += v1; tq1 += v1 * v1;
      }
    }
    atomicAdd(&ssum[ob], ts0); atomicAdd(&ssq[ob], tq0);
    atomicAdd(&ssum[ob + 1], ts1); atomicAdd(&ssq[ob + 1], tq1);
  }
  __syncthreads();
  if (tid < 48) { atomicAdd(&sum[tid], ssum[tid]); atomicAdd(&sq[tid], ssq[tid]); }
}

// ============================ Stage 4 ============================
// 384 threads: (bb8, op24, kh2: cp 0-11 / 12-23), shfl reduction; 2 o-chunks.
#define NB4 8
template<int I2>
__device__ __forceinline__ void s4h(const hf2* __restrict__ rr, int h,
    const hf2* __restrict__ w0, const hf2* __restrict__ w1, float* __restrict__ acc) {
  constexpr int S = 1 << I2;
  const int base = (I2 + h) * 3;
#pragma unroll
  for (int j = 0; j < 3; ++j) {
    const int off = S * (j - 1);
    if (off <= -3 || off >= 3) continue;
    if (off >= 0) {
      acc[0] = fdot2h(rr[base + off], w0[j], acc[0]);
      acc[2] = fdot2h(rr[base + off], w1[j], acc[2]);
    }
    const int i1 = 1 + off;
    if (i1 >= 0 && i1 < 3) {
      acc[1] = fdot2h(rr[base + i1], w0[j], acc[1]);
      acc[3] = fdot2h(rr[base + i1], w1[j], acc[3]);
    }
  }
}

__global__ __launch_bounds__(384) void k_stage4(const unsigned* __restrict__ r3,
    const __half* __restrict__ W4P,
    const float* __restrict__ SUM, const float* __restrict__ SQ,
    const float* __restrict__ g, const float* __restrict__ bbn, float invN,
    float* __restrict__ r4, float* __restrict__ sum, float* __restrict__ sq) {
  __shared__ __align__(16) unsigned asu[NB4 * 361];
  __shared__ __align__(16) unsigned wlu[10368];
  __shared__ float ssum[96], ssq[96];
  __shared__ float scf[48], shf[48];
  int b0 = blockIdx.x * NB4, tid = threadIdx.x;
  if (tid < 48) {
    float m = SUM[tid] * invN;
    float v = SQ[tid] * invN - m * m;
    float scale = g[tid] * rsqrtf(v + EPSBN);
    scf[tid] = scale; shf[tid] = bbn[tid] - m * scale;
  }
  if (tid < 96) { ssum[tid] = 0.f; ssq[tid] = 0.f; }
  __syncthreads();
  for (int i = tid; i < NB4 * 360; i += 384) {
    int bb = i / 360, f = i % 360, cp = f / 15;
    int c0 = 2 * cp, c1 = c0 + 1;
    float2 a = uph(r3[(size_t)(b0 + bb) * 360 + f]);
    asu[bb * 361 + f] = pk(a.x * scf[c0] + shf[c0], a.y * scf[c1] + shf[c1]);
  }
  int wv = tid >> 6, lane = tid & 63;
  int kh = lane & 1;
  int w = wv * 32 + (lane >> 1);
  int bb = w / 24, op = w % 24;
  int b = b0 + bb;
  int cp0 = kh * 12;
  for (int chunk = 0; chunk < 2; ++chunk) {
    __syncthreads();
    for (int i = tid; i < 2592; i += 384)
      ((uint4*)wlu)[i] = ((const uint4*)W4P)[chunk * 2592 + i];
    __syncthreads();
    float acc[12];
#pragma unroll
    for (int k = 0; k < 12; ++k) acc[k] = 0.f;
#pragma unroll 1
    for (int cp = cp0; cp < cp0 + 12; ++cp) {
      const hf2* ar = (const hf2*)(asu + bb * 361 + cp * 15);
      hf2 rr[15];
#pragma unroll
      for (int k = 0; k < 15; ++k) rr[k] = ar[k];
#pragma unroll
      for (int h = 0; h < 3; ++h) {
        const unsigned* wp = wlu + ((cp * 3 + h) * 3) * 48 + op * 2;
        hf2 w0[3], w1[3];
#pragma unroll
        for (int j = 0; j < 3; ++j) {
          w0[j] = *(const hf2*)(wp + j * 48);
          w1[j] = *(const hf2*)(wp + j * 48 + 1);
        }
        s4h<0>(rr, h, w0, w1, acc);
        s4h<1>(rr, h, w0, w1, acc + 4);
        s4h<2>(rr, h, w0, w1, acc + 8);
      }
    }
#pragma unroll
    for (int k = 0; k < 12; ++k) acc[k] += __shfl_xor(acc[k], 1);
    if (kh == 0) {
      int o0 = chunk * 48 + op * 2;
#pragma unroll
      for (int oo = 0; oo < 2; ++oo) {
        float ts = 0.f, tq = 0.f;
#pragma unroll
        for (int i2 = 0; i2 < 3; ++i2) {
          const float inv = 1.0f / (float)(1 << i2);
          float v = fmaxf(fmaxf(acc[i2 * 4 + oo * 2], acc[i2 * 4 + oo * 2 + 1]) * inv, 0.f);
          r4[(size_t)b * 288 + (o0 + oo) * 3 + i2] = v;
          ts += v; tq += v * v;
        }
        atomicAdd(&ssum[o0 + oo], ts); atomicAdd(&ssq[o0 + oo], tq);
      }
    }
  }
  __syncthreads();
  if (tid < 96) { atomicAdd(&sum[tid], ssum[tid]); atomicAdd(&sq[tid], ssq[tid]); }
}

// ---------------- FC head: BN4-affine + 288->96->48->6 ----------------
__global__ __launch_bounds__(256) void k_fc(const float* __restrict__ r4,
    const float* __restrict__ SUM, const float* __restrict__ SQ,
    const float* __restrict__ g, const float* __restrict__ bbn, float invN,
    const float* __restrict__ f1w, const float* __restrict__ f1b,
    const float* __restrict__ f2w, const float* __restrict__ f2b,
    const float* __restrict__ f3w, const float* __restrict__ f3b,
    float* __restrict__ out) {
  __shared__ float v[4][288];
  __shared__ float h1[4][96];
  __shared__ float h2[4][48];
  __shared__ float scf[96], shf[96];
  int b0 = blockIdx.x * 4, tid = threadIdx.x;
  if (tid < 96) {
    float m = SUM[tid] * invN;
    float vv = SQ[tid] * invN - m * m;
    float scale = g[tid] * rsqrtf(vv + EPSBN);
    scf[tid] = scale; shf[tid] = bbn[tid] - m * scale;
  }
  __syncthreads();
  for (int i = tid; i < 4 * 288; i += 256) {
    int bb = i / 288, f = i % 288, c = f / 3;
    v[bb][f] = r4[(size_t)(b0 + bb) * 288 + f] * scf[c] + shf[c];
  }
  __syncthreads();
  for (int d = tid; d < 384; d += 256) {
    int o = d >> 2, bb = d & 3;
    const float* wr = &f1w[o * 288];
    const float* vv = v[bb];
    float acc = f1b[o];
    for (int f = 0; f < 288; ++f) acc += wr[f] * vv[f];
    h1[bb][o] = acc;
  }
  __syncthreads();
  if (tid < 192) {
    int o = tid >> 2, bb = tid & 3;
    const float* wr = &f2w[o * 96];
    float acc = f2b[o];
    for (int f = 0; f < 96; ++f) acc += wr[f] * h1[bb][f];
    h2[bb][o] = acc;
  }
  __syncthreads();
  if (tid < 24) {
    int o = tid >> 2, bb = tid & 3;
    const float* wr = &f3w[o * 48];
    float acc = f3b[o];
    for (int f = 0; f < 48; ++f) acc += wr[f] * h2[bb][f];
    out[(size_t)(b0 + bb) * 6 + o] = acc;
  }
}

extern "C" void kernel_launch(void* const* d_in, const int* in_sizes, int n_in,
                              void* d_out, int out_size, void* d_ws, size_t ws_size,
                              hipStream_t stream) {
  const float* x   = (const float*)d_in[0];
  const float* w1  = (const float*)d_in[1];
  const float* w2  = (const float*)d_in[2];
  const float* w3  = (const float*)d_in[3];
  const float* w4  = (const float*)d_in[4];
  const float* g1  = (const float*)d_in[5];
  const float* b1  = (const float*)d_in[6];
  const float* g2  = (const float*)d_in[7];
  const float* b2  = (const float*)d_in[8];
  const float* g3  = (const float*)d_in[9];
  const float* b3  = (const float*)d_in[10];
  const float* g4  = (const float*)d_in[11];
  const float* b4  = (const float*)d_in[12];
  const float* f1w = (const float*)d_in[13];
  const float* f1b = (const float*)d_in[14];
  const float* f2w = (const float*)d_in[15];
  const float* f2b = (const float*)d_in[16];
  const float* f3w = (const float*)d_in[17];
  const float* f3b = (const float*)d_in[18];
  float* out = (float*)d_out;
  float* ws = (float*)d_ws;

  const int B = 4096;
  float* SUM1 = ws + 0;   float* SQ1 = ws + 12;
  float* SUM2 = ws + 24;  float* SQ2 = ws + 48;
  float* SUM3 = ws + 72;  float* SQ3 = ws + 120;
  float* SUM4 = ws + 168; float* SQ4 = ws + 264;
  __half* H0  = (__half*)(ws + 1024);
  __half* W2P = H0;                         // 4320 halfs
  __half* W3P = H0 + 4320;                  // 17280
  __half* W4P = H0 + 21600;                 // 41472
  __half* R1h = H0 + 65536;                 // B*5400 halfs
  unsigned* R2P = (unsigned*)(R1h + (size_t)B * 5400);  // B*504 dwords
  unsigned* R3D = (unsigned*)R1h;                        // alias, B*360 dwords
  float*  R4  = (float*)(R2P + (size_t)B * 504);         // B*288 floats

  hipMemsetAsync(d_ws, 0, 384 * sizeof(float), stream);

  k_lift<<<B / NB1, 512, 0, stream>>>(x, w1, w2, w3, w4, W2P, W3P, W4P, R1h, SUM1, SQ1);
  k_stage2<<<(B + NB2 - 1) / NB2, 512, 0, stream>>>(R1h, W2P, SUM1, SQ1, g1, b1,
      1.0f / (float)(B * 450), R2P, SUM2, SQ2, B);
  k_stage3<<<B / NB3, 384, 0, stream>>>(R2P, W3P, SUM2, SQ2, g2, b2,
      1.0f / (float)(B * 84), R3D, SUM3, SQ3);
  k_stage4<<<B / NB4, 384, 0, stream>>>(R3D, W4P, SUM3, SQ3, g3, b3,
      1.0f / (float)(B * 15), R4, SUM4, SQ4);
  k_fc<<<B / 4, 256, 0, stream>>>(R4, SUM4, SQ4, g4, b4,
      1.0f / (float)(B * 3), f1w, f1b, f2w, f2b, f3w, f3b, out);
}

// Round 11
// 300.380 us; speedup vs baseline: 1.0442x; 1.0442x over previous
//
#include <hip/hip_runtime.h>
#include <hip/hip_fp16.h>

#define EPSBN 2e-5f

typedef _Float16 hf2 __attribute__((ext_vector_type(2)));
typedef _Float16 hf4 __attribute__((ext_vector_type(4)));
typedef _Float16 hf8 __attribute__((ext_vector_type(8)));
union U8 { hf8 v; hf2 p[4]; };

static __device__ __forceinline__ float fdot2h(hf2 a, hf2 b, float c) {
  return __builtin_amdgcn_fdot2(a, b, c, false);
}
static __device__ __forceinline__ unsigned pk(float a, float b) {
  union { __half2 h; unsigned u; } u;
  u.h = __floats2half2_rn(a, b);
  return u.u;
}
static __device__ __forceinline__ float2 uph(unsigned v) {
  union { unsigned u; __half2 h; } x; x.u = v;
  return __half22float2(x.h);
}

// ============================ Stage 1: lift (+ folded weight prep) ============
// x:(B,100,6) -> LDS half2 c-pairs, zero-padded rows (stride 296 dw, 96 left pad).
// Thread=(bb4, op6, tc10)=240. r1 fp16 (B,12,9,50). b64 x-window loads.
#define NB1 4
template<int SI>
__device__ __forceinline__ void s1_si(const unsigned* __restrict__ xsu, int bb, int t0,
    const unsigned* __restrict__ wlu, int o0, bool act, int b,
    __half* __restrict__ r1, float& ts0, float& tq0, float& ts1, float& tq1) {
  constexpr int S = 1 << SI;
  float a0[10], a1[10];
#pragma unroll
  for (int k = 0; k < 10; ++k) { a0[k] = 0.f; a1[k] = 0.f; }
#pragma unroll 1
  for (int cp = 0; cp < 3; ++cp) {
    const hf2* xr = (const hf2*)xsu + (bb * 3 + cp) * 296 + 96 + t0;  // even dword base
    const unsigned* wp = wlu + cp * 84;
#pragma unroll
    for (int j = 0; j < 7; ++j) {
      const int off = S * (j - 3);
      if (off < -96 || off > 98) continue;   // compile-time dead tap
      const int offE = off & ~1;             // even floor (compile-time)
      const int sh = off & 1;                // compile-time shift
      hf2 w0 = *(const hf2*)(wp + j * 12 + o0);
      hf2 w1 = *(const hf2*)(wp + j * 12 + o0 + 1);
      hf2 xv[12];
#pragma unroll
      for (int q = 0; q < 6; ++q) {
        hf4 bufq = *(const hf4*)(xr + offE + 2 * q);   // aligned b64
        xv[2 * q] = bufq.lo; xv[2 * q + 1] = bufq.hi;
      }
#pragma unroll
      for (int k = 0; k < 10; ++k) {
        a0[k] = fdot2h(xv[sh + k], w0, a0[k]);
        a1[k] = fdot2h(xv[sh + k], w1, a1[k]);
      }
    }
  }
  if (act) {
    const float inv = 1.0f / (float)S;
    size_t rb = ((size_t)b * 12 + o0) * 9 + SI;
#pragma unroll
    for (int u = 0; u < 5; ++u) {
      float v0 = fmaxf(fmaxf(a0[2 * u], a0[2 * u + 1]) * inv, 0.f);
      float v1 = fmaxf(fmaxf(a1[2 * u], a1[2 * u + 1]) * inv, 0.f);
      r1[rb * 50 + (t0 >> 1) + u] = __float2half_rn(v0);
      r1[(rb + 9) * 50 + (t0 >> 1) + u] = __float2half_rn(v1);
      ts0 += v0; tq0 += v0 * v0; ts1 += v1; tq1 += v1 * v1;
    }
  }
}

__global__ __launch_bounds__(256) void k_lift(const float* __restrict__ x,
    const float* __restrict__ w1, const float* __restrict__ w2,
    const float* __restrict__ w3, const float* __restrict__ w4,
    __half* __restrict__ W2P, __half* __restrict__ W3P, __half* __restrict__ W4P,
    __half* __restrict__ r1, float* __restrict__ sum, float* __restrict__ sq) {
  __shared__ __align__(16) unsigned xsu[NB1 * 888];   // [bb][cp3][296 dw]
  __shared__ __align__(16) unsigned wlu[252];
  __shared__ float ssum[12], ssq[12];
  int b0 = blockIdx.x * NB1, tid = threadIdx.x;
  // ---- folded weight prep: one element per thread grid-wide ----
  {
    int gi = blockIdx.x * 256 + tid;
    if (gi < 4320) {
      int ci = gi & 1, r = gi >> 1, o = r % 24, j = (r / 24) % 5, h = (r / 120) % 3, cp = r / 360;
      int c = 2 * cp + ci;
      W2P[gi] = __float2half_rn(w2[((o * 12 + c) * 3 + h) * 5 + j]);
    } else if (gi < 21600) {
      int k = gi - 4320;
      int ci = k & 1, r = k >> 1, o = r % 48, j = (r / 48) % 5, h = (r / 240) % 3, cp = r / 720;
      int c = 2 * cp + ci;
      W3P[k] = __float2half_rn(w3[((o * 24 + c) * 3 + h) * 5 + j]);
    } else if (gi < 63072) {
      int k = gi - 21600;
      int ci = k & 1, r = k >> 1, o48 = r % 48, j = (r / 48) % 3, h = (r / 144) % 3;
      int cp = (r / 432) % 24, ch = r / 10368, c = 2 * cp + ci, o = ch * 48 + o48;
      W4P[k] = __float2half_rn(w4[((o * 48 + c) * 3 + h) * 3 + j]);
    }
  }
  for (int i = tid; i < NB1 * 888; i += 256) xsu[i] = 0u;
  for (int i = tid; i < 252; i += 256) {
    int cp = i / 84, j = (i % 84) / 12, o = i % 12;
    wlu[i] = pk(w1[(o * 6 + 2 * cp) * 7 + j], w1[(o * 6 + 2 * cp + 1) * 7 + j]);
  }
  if (tid < 12) { ssum[tid] = 0.f; ssq[tid] = 0.f; }
  __syncthreads();
  __half* xsh = (__half*)xsu;
  for (int i = tid; i < NB1 * 600; i += 256) {
    int bb = i / 600, f = i % 600, t = f / 6, c = f % 6;
    xsh[((bb * 3 + (c >> 1)) * 296 + 96 + t) * 2 + (c & 1)] =
        __float2half_rn(x[(size_t)(b0 + bb) * 600 + f]);
  }
  __syncthreads();
  bool act = tid < 240;
  int task = act ? tid : 0;
  int bb = task / 60, r = task % 60;
  int op = r / 10, tc = r % 10;
  int o0 = op * 2, t0 = tc * 10;
  int b = b0 + bb;
  float ts0 = 0.f, tq0 = 0.f, ts1 = 0.f, tq1 = 0.f;
  s1_si<0>(xsu, bb, t0, wlu, o0, act, b, r1, ts0, tq0, ts1, tq1);
  s1_si<1>(xsu, bb, t0, wlu, o0, act, b, r1, ts0, tq0, ts1, tq1);
  s1_si<2>(xsu, bb, t0, wlu, o0, act, b, r1, ts0, tq0, ts1, tq1);
  s1_si<3>(xsu, bb, t0, wlu, o0, act, b, r1, ts0, tq0, ts1, tq1);
  s1_si<4>(xsu, bb, t0, wlu, o0, act, b, r1, ts0, tq0, ts1, tq1);
  s1_si<5>(xsu, bb, t0, wlu, o0, act, b, r1, ts0, tq0, ts1, tq1);
  s1_si<6>(xsu, bb, t0, wlu, o0, act, b, r1, ts0, tq0, ts1, tq1);
  s1_si<7>(xsu, bb, t0, wlu, o0, act, b, r1, ts0, tq0, ts1, tq1);
  s1_si<8>(xsu, bb, t0, wlu, o0, act, b, r1, ts0, tq0, ts1, tq1);
  if (act) {
    atomicAdd(&ssum[o0], ts0); atomicAdd(&ssq[o0], tq0);
    atomicAdd(&ssum[o0 + 1], ts1); atomicAdd(&ssq[o0 + 1], tq1);
  }
  __syncthreads();
  if (tid < 12) { atomicAdd(&sum[tid], ssum[tid]); atomicAdd(&sq[tid], ssq[tid]); }
}

// ============================ Stage 2 ============================
// Round-9 structure (lanes bb5 x op12, 4 i2-wave-groups). LDS rows padded to
// 28 dwords -> rr via 7x b128; w0/w1 via single b64.
#define NB2 5
template<int S, int I2>
__device__ __forceinline__ void s2_do(const unsigned* __restrict__ abu,
    const unsigned* __restrict__ wlu, int op, bool act, int b,
    unsigned* __restrict__ r2p, float& ts0, float& tq0, float& ts1, float& tq1) {
  float acc0[24], acc1[24];
#pragma unroll
  for (int t = 0; t < 24; ++t) { acc0[t] = 0.f; acc1[t] = 0.f; }
#pragma unroll 1
  for (int cp = 0; cp < 6; ++cp) {
#pragma unroll
    for (int h = 0; h < 3; ++h) {
      const unsigned* ar = abu + (cp * 9 + I2 + h) * 28;   // 16B-aligned row
      hf2 rr[28];
#pragma unroll
      for (int q = 0; q < 7; ++q) {
        U8 u; u.v = *(const hf8*)(ar + 4 * q);
        rr[4 * q] = u.p[0]; rr[4 * q + 1] = u.p[1];
        rr[4 * q + 2] = u.p[2]; rr[4 * q + 3] = u.p[3];
      }
      const unsigned* wp = wlu + ((cp * 3 + h) * 5) * 24 + op * 2;
#pragma unroll
      for (int j = 0; j < 5; ++j) {
        const int off = S * (j - 2);
        if (off <= -25 || off >= 25) continue;
        hf4 w01 = *(const hf4*)(wp + j * 24);
        hf2 w0 = w01.lo, w1 = w01.hi;
#pragma unroll
        for (int t = 0; t < 24; ++t) {
          if (t + off >= 0 && t + off < 25) {
            acc0[t] = fdot2h(rr[t + off], w0, acc0[t]);
            acc1[t] = fdot2h(rr[t + off], w1, acc1[t]);
          }
        }
      }
    }
  }
  if (act) {
    const float inv = 1.0f / (float)S;
    unsigned* pd = r2p + ((size_t)b * 12 + op) * 42 + I2 * 6;
    float m0 = 0.f, m1 = 0.f;
#pragma unroll
    for (int u = 0; u < 12; ++u) {
      float v0 = fmaxf(fmaxf(acc0[2 * u], acc0[2 * u + 1]) * inv, 0.f);
      float v1 = fmaxf(fmaxf(acc1[2 * u], acc1[2 * u + 1]) * inv, 0.f);
      ts0 += v0; tq0 += v0 * v0; ts1 += v1; tq1 += v1 * v1;
      if ((u & 1) == 0) { m0 = v0; m1 = v1; }
      else pd[u >> 1] = pk(fmaxf(m0, v0), fmaxf(m1, v1));
    }
  }
}

__global__ __launch_bounds__(256) void k_stage2(const __half* __restrict__ r1,
    const __half* __restrict__ W2P,
    const float* __restrict__ SUM, const float* __restrict__ SQ,
    const float* __restrict__ g, const float* __restrict__ bbn, float invN,
    unsigned* __restrict__ r2p, float* __restrict__ sum, float* __restrict__ sq, int B) {
  __shared__ __align__(16) unsigned asu[NB2 * 1512];   // rows stride 28, bb stride 1512
  __shared__ __align__(16) unsigned wlu[2160];
  __shared__ float ssum[24], ssq[24];
  __shared__ float scf[12], shf[12];
  int b0 = blockIdx.x * NB2, tid = threadIdx.x;
  if (tid < 12) {
    float m = SUM[tid] * invN;
    float v = SQ[tid] * invN - m * m;
    float scale = g[tid] * rsqrtf(v + EPSBN);
    scf[tid] = scale; shf[tid] = bbn[tid] - m * scale;
    ssum[tid] = 0.f; ssq[tid] = 0.f;
    ssum[tid + 12] = 0.f; ssq[tid + 12] = 0.f;
  }
  __syncthreads();
  for (int i = tid; i < NB2 * 1350; i += 256) {
    int bb = i / 1350, s = i % 1350;
    if (b0 + bb < B) {
      int cp = s / 225, rem = s % 225, row = rem / 25, t = rem % 25;
      int c0 = 2 * cp, c1 = c0 + 1;
      float2 a0 = __half22float2(*(const __half2*)(r1 +
          (((size_t)(b0 + bb) * 12 + c0) * 9 + row) * 50 + 2 * t));
      float2 a1 = __half22float2(*(const __half2*)(r1 +
          (((size_t)(b0 + bb) * 12 + c1) * 9 + row) * 50 + 2 * t));
      float v0 = fmaxf(a0.x, a0.y) * scf[c0] + shf[c0];
      float v1 = fmaxf(a1.x, a1.y) * scf[c1] + shf[c1];
      asu[bb * 1512 + (cp * 9 + row) * 28 + t] = pk(v0, v1);
    }
  }
  for (int i = tid; i < 540; i += 256)
    ((uint4*)wlu)[i] = ((const uint4*)W2P)[i];
  __syncthreads();
  int wv = tid >> 6, lane = tid & 63;
  int bb = lane / 12, op = lane % 12;
  bool act = (lane < 60) && (b0 + bb < B);
  if (bb > 4) bb = 4;
  const unsigned* abu = asu + bb * 1512;
  int b = b0 + bb;
  float ts0 = 0.f, tq0 = 0.f, ts1 = 0.f, tq1 = 0.f;
  if (wv == 0) {
    s2_do<1, 0>(abu, wlu, op, act, b, r2p, ts0, tq0, ts1, tq1);
  } else if (wv == 1) {
    s2_do<2, 1>(abu, wlu, op, act, b, r2p, ts0, tq0, ts1, tq1);
    s2_do<64, 6>(abu, wlu, op, act, b, r2p, ts0, tq0, ts1, tq1);
  } else if (wv == 2) {
    s2_do<4, 2>(abu, wlu, op, act, b, r2p, ts0, tq0, ts1, tq1);
    s2_do<32, 5>(abu, wlu, op, act, b, r2p, ts0, tq0, ts1, tq1);
  } else {
    s2_do<8, 3>(abu, wlu, op, act, b, r2p, ts0, tq0, ts1, tq1);
    s2_do<16, 4>(abu, wlu, op, act, b, r2p, ts0, tq0, ts1, tq1);
  }
  if (act) {
    int o0 = op * 2;
    atomicAdd(&ssum[o0], ts0); atomicAdd(&ssq[o0], tq0);
    atomicAdd(&ssum[o0 + 1], ts1); atomicAdd(&ssq[o0 + 1], tq1);
  }
  __syncthreads();
  if (tid < 24) { atomicAdd(&sum[tid], ssum[tid]); atomicAdd(&sq[tid], ssq[tid]); }
}

// ============================ Stage 3 ============================
// Round-9 structure (bb8, op24). cp blocks padded to 44 dw, bb stride 536
// (mod32=24). rr via 11x b128; weights via b64.
#define NB3 8
template<int I2>
__device__ __forceinline__ void s3h(const hf2* __restrict__ rr, int h,
    const hf2* __restrict__ w0, const hf2* __restrict__ w1, float* __restrict__ acc) {
  constexpr int S = 1 << I2;
  const int base = (I2 + h) * 6;
#pragma unroll
  for (int j = 0; j < 5; ++j) {
    const int off = S * (j - 2);
    if (off <= -6 || off >= 6) continue;
#pragma unroll
    for (int t = 0; t < 6; ++t) {
      if (t + off >= 0 && t + off < 6) {
        acc[t] = fdot2h(rr[base + t + off], w0[j], acc[t]);
        acc[6 + t] = fdot2h(rr[base + t + off], w1[j], acc[6 + t]);
      }
    }
  }
}

__global__ __launch_bounds__(256) void k_stage3(const unsigned* __restrict__ r2p,
    const __half* __restrict__ W3P,
    const float* __restrict__ SUM, const float* __restrict__ SQ,
    const float* __restrict__ g, const float* __restrict__ bbn, float invN,
    unsigned* __restrict__ r3, float* __restrict__ sum, float* __restrict__ sq) {
  __shared__ __align__(16) unsigned asu[NB3 * 536];
  __shared__ __align__(16) unsigned wlu[8640];
  __shared__ float ssum[48], ssq[48];
  __shared__ float scf[24], shf[24];
  int b0 = blockIdx.x * NB3, tid = threadIdx.x;
  if (tid < 24) {
    float m = SUM[tid] * invN;
    float v = SQ[tid] * invN - m * m;
    float scale = g[tid] * rsqrtf(v + EPSBN);
    scf[tid] = scale; shf[tid] = bbn[tid] - m * scale;
  }
  if (tid < 48) { ssum[tid] = 0.f; ssq[tid] = 0.f; }
  __syncthreads();
  for (int i = tid; i < NB3 * 504; i += 256) {
    int bb = i / 504, f = i % 504, cp = f / 42, r42 = f % 42;
    int c0 = 2 * cp, c1 = c0 + 1;
    float2 a = uph(r2p[(size_t)(b0 + bb) * 504 + f]);
    asu[bb * 536 + cp * 44 + r42] = pk(a.x * scf[c0] + shf[c0], a.y * scf[c1] + shf[c1]);
  }
  for (int i = tid; i < 2160; i += 256)
    ((uint4*)wlu)[i] = ((const uint4*)W3P)[i];
  __syncthreads();
  bool act = tid < 192;
  int bb = act ? tid / 24 : 0, op = tid % 24;
  int b = b0 + bb;
  if (act) {
    float acc[60];
#pragma unroll
    for (int k = 0; k < 60; ++k) acc[k] = 0.f;
#pragma unroll 1
    for (int cp = 0; cp < 12; ++cp) {
      const unsigned* ar = asu + bb * 536 + cp * 44;
      hf2 rr[44];
#pragma unroll
      for (int q = 0; q < 11; ++q) {
        U8 u; u.v = *(const hf8*)(ar + 4 * q);
        rr[4 * q] = u.p[0]; rr[4 * q + 1] = u.p[1];
        rr[4 * q + 2] = u.p[2]; rr[4 * q + 3] = u.p[3];
      }
#pragma unroll
      for (int h = 0; h < 3; ++h) {
        const unsigned* wp = wlu + (cp * 15 + h * 5) * 48 + op * 2;
        hf2 w0[5], w1[5];
#pragma unroll
        for (int j = 0; j < 5; ++j) {
          hf4 w01 = *(const hf4*)(wp + j * 48);
          w0[j] = w01.lo; w1[j] = w01.hi;
        }
        s3h<0>(rr, h, w0, w1, acc);
        s3h<1>(rr, h, w0, w1, acc + 12);
        s3h<2>(rr, h, w0, w1, acc + 24);
        s3h<3>(rr, h, w0, w1, acc + 36);
        s3h<4>(rr, h, w0, w1, acc + 48);
      }
    }
    float ts0 = 0.f, tq0 = 0.f, ts1 = 0.f, tq1 = 0.f;
    int ob = op * 2;
#pragma unroll
    for (int i2 = 0; i2 < 5; ++i2) {
      const float inv = 1.0f / (float)(1 << i2);
      size_t rb = ((size_t)b * 24 + op) * 15 + i2 * 3;
#pragma unroll
      for (int u = 0; u < 3; ++u) {
        float v0 = fmaxf(fmaxf(acc[i2 * 12 + 2 * u], acc[i2 * 12 + 2 * u + 1]) * inv, 0.f);
        float v1 = fmaxf(fmaxf(acc[i2 * 12 + 6 + 2 * u], acc[i2 * 12 + 7 + 2 * u]) * inv, 0.f);
        r3[rb + u] = pk(v0, v1);
        ts0 += v0; tq0 += v0 * v0; ts1 += v1; tq1 += v1 * v1;
      }
    }
    atomicAdd(&ssum[ob], ts0); atomicAdd(&ssq[ob], tq0);
    atomicAdd(&ssum[ob + 1], ts1); atomicAdd(&ssq[ob + 1], tq1);
  }
  __syncthreads();
  if (tid < 48) { atomicAdd(&sum[tid], ssum[tid]); atomicAdd(&sq[tid], ssq[tid]); }
}

// ============================ Stage 4 ============================
// Round-9 structure (bb8, op24, 2 o-chunks). cp rows padded to 16 dw,
// bb stride 392 (mod32=8). rr via 4x b128; weights via b64.
#define NB4 8
template<int I2>
__device__ __forceinline__ void s4h(const hf2* __restrict__ rr, int h,
    const hf2* __restrict__ w0, const hf2* __restrict__ w1, float* __restrict__ acc) {
  constexpr int S = 1 << I2;
  const int base = (I2 + h) * 3;
#pragma unroll
  for (int j = 0; j < 3; ++j) {
    const int off = S * (j - 1);
    if (off <= -3 || off >= 3) continue;
    if (off >= 0) {
      acc[0] = fdot2h(rr[base + off], w0[j], acc[0]);
      acc[2] = fdot2h(rr[base + off], w1[j], acc[2]);
    }
    const int i1 = 1 + off;
    if (i1 >= 0 && i1 < 3) {
      acc[1] = fdot2h(rr[base + i1], w0[j], acc[1]);
      acc[3] = fdot2h(rr[base + i1], w1[j], acc[3]);
    }
  }
}

__global__ __launch_bounds__(256) void k_stage4(const unsigned* __restrict__ r3,
    const __half* __restrict__ W4P,
    const float* __restrict__ SUM, const float* __restrict__ SQ,
    const float* __restrict__ g, const float* __restrict__ bbn, float invN,
    float* __restrict__ r4, float* __restrict__ sum, float* __restrict__ sq) {
  __shared__ __align__(16) unsigned asu[NB4 * 392];
  __shared__ __align__(16) unsigned wlu[10368];
  __shared__ float ssum[96], ssq[96];
  __shared__ float scf[48], shf[48];
  int b0 = blockIdx.x * NB4, tid = threadIdx.x;
  if (tid < 48) {
    float m = SUM[tid] * invN;
    float v = SQ[tid] * invN - m * m;
    float scale = g[tid] * rsqrtf(v + EPSBN);
    scf[tid] = scale; shf[tid] = bbn[tid] - m * scale;
  }
  if (tid < 96) { ssum[tid] = 0.f; ssq[tid] = 0.f; }
  __syncthreads();
  for (int i = tid; i < NB4 * 360; i += 256) {
    int bb = i / 360, f = i % 360, cp = f / 15, r15 = f % 15;
    int c0 = 2 * cp, c1 = c0 + 1;
    float2 a = uph(r3[(size_t)(b0 + bb) * 360 + f]);
    asu[bb * 392 + cp * 16 + r15] = pk(a.x * scf[c0] + shf[c0], a.y * scf[c1] + shf[c1]);
  }
  bool act = tid < 192;
  int bb = act ? tid / 24 : 0, op = tid % 24;
  int b = b0 + bb;
  for (int chunk = 0; chunk < 2; ++chunk) {
    __syncthreads();
    for (int i = tid; i < 2592; i += 256)
      ((uint4*)wlu)[i] = ((const uint4*)W4P)[chunk * 2592 + i];
    __syncthreads();
    if (act) {
      float acc[12];   // [i2 3][o2][t2]
#pragma unroll
      for (int k = 0; k < 12; ++k) acc[k] = 0.f;
#pragma unroll 1
      for (int cp = 0; cp < 24; ++cp) {
        const unsigned* ar = asu + bb * 392 + cp * 16;
        hf2 rr[16];
#pragma unroll
        for (int q = 0; q < 4; ++q) {
          U8 u; u.v = *(const hf8*)(ar + 4 * q);
          rr[4 * q] = u.p[0]; rr[4 * q + 1] = u.p[1];
          rr[4 * q + 2] = u.p[2]; rr[4 * q + 3] = u.p[3];
        }
#pragma unroll
        for (int h = 0; h < 3; ++h) {
          const unsigned* wp = wlu + ((cp * 3 + h) * 3) * 48 + op * 2;
          hf2 w0[3], w1[3];
#pragma unroll
          for (int j = 0; j < 3; ++j) {
            hf4 w01 = *(const hf4*)(wp + j * 48);
            w0[j] = w01.lo; w1[j] = w01.hi;
          }
          s4h<0>(rr, h, w0, w1, acc);
          s4h<1>(rr, h, w0, w1, acc + 4);
          s4h<2>(rr, h, w0, w1, acc + 8);
        }
      }
      int o0 = chunk * 48 + op * 2;
#pragma unroll
      for (int oo = 0; oo < 2; ++oo) {
        float ts = 0.f, tq = 0.f;
#pragma unroll
        for (int i2 = 0; i2 < 3; ++i2) {
          const float inv = 1.0f / (float)(1 << i2);
          float v = fmaxf(fmaxf(acc[i2 * 4 + oo * 2], acc[i2 * 4 + oo * 2 + 1]) * inv, 0.f);
          r4[(size_t)b * 288 + (o0 + oo) * 3 + i2] = v;
          ts += v; tq += v * v;
        }
        atomicAdd(&ssum[o0 + oo], ts); atomicAdd(&ssq[o0 + oo], tq);
      }
    }
  }
  __syncthreads();
  if (tid < 96) { atomicAdd(&sum[tid], ssum[tid]); atomicAdd(&sq[tid], ssq[tid]); }
}

// ---------------- FC head: BN4-affine + 288->96->48->6 ----------------
__global__ __launch_bounds__(256) void k_fc(const float* __restrict__ r4,
    const float* __restrict__ SUM, const float* __restrict__ SQ,
    const float* __restrict__ g, const float* __restrict__ bbn, float invN,
    const float* __restrict__ f1w, const float* __restrict__ f1b,
    const float* __restrict__ f2w, const float* __restrict__ f2b,
    const float* __restrict__ f3w, const float* __restrict__ f3b,
    float* __restrict__ out) {
  __shared__ float v[4][288];
  __shared__ float h1[4][96];
  __shared__ float h2[4][48];
  __shared__ float scf[96], shf[96];
  int b0 = blockIdx.x * 4, tid = threadIdx.x;
  if (tid < 96) {
    float m = SUM[tid] * invN;
    float vv = SQ[tid] * invN - m * m;
    float scale = g[tid] * rsqrtf(vv + EPSBN);
    scf[tid] = scale; shf[tid] = bbn[tid] - m * scale;
  }
  __syncthreads();
  for (int i = tid; i < 4 * 288; i += 256) {
    int bb = i / 288, f = i % 288, c = f / 3;
    v[bb][f] = r4[(size_t)(b0 + bb) * 288 + f] * scf[c] + shf[c];
  }
  __syncthreads();
  for (int d = tid; d < 384; d += 256) {
    int o = d >> 2, bb = d & 3;
    const float* wr = &f1w[o * 288];
    const float* vv = v[bb];
    float acc = f1b[o];
    for (int f = 0; f < 288; ++f) acc += wr[f] * vv[f];
    h1[bb][o] = acc;
  }
  __syncthreads();
  if (tid < 192) {
    int o = tid >> 2, bb = tid & 3;
    const float* wr = &f2w[o * 96];
    float acc = f2b[o];
    for (int f = 0; f < 96; ++f) acc += wr[f] * h1[bb][f];
    h2[bb][o] = acc;
  }
  __syncthreads();
  if (tid < 24) {
    int o = tid >> 2, bb = tid & 3;
    const float* wr = &f3w[o * 48];
    float acc = f3b[o];
    for (int f = 0; f < 48; ++f) acc += wr[f] * h2[bb][f];
    out[(size_t)(b0 + bb) * 6 + o] = acc;
  }
}

extern "C" void kernel_launch(void* const* d_in, const int* in_sizes, int n_in,
                              void* d_out, int out_size, void* d_ws, size_t ws_size,
                              hipStream_t stream) {
  const float* x   = (const float*)d_in[0];
  const float* w1  = (const float*)d_in[1];
  const float* w2  = (const float*)d_in[2];
  const float* w3  = (const float*)d_in[3];
  const float* w4  = (const float*)d_in[4];
  const float* g1  = (const float*)d_in[5];
  const float* b1  = (const float*)d_in[6];
  const float* g2  = (const float*)d_in[7];
  const float* b2  = (const float*)d_in[8];
  const float* g3  = (const float*)d_in[9];
  const float* b3  = (const float*)d_in[10];
  const float* g4  = (const float*)d_in[11];
  const float* b4  = (const float*)d_in[12];
  const float* f1w = (const float*)d_in[13];
  const float* f1b = (const float*)d_in[14];
  const float* f2w = (const float*)d_in[15];
  const float* f2b = (const float*)d_in[16];
  const float* f3w = (const float*)d_in[17];
  const float* f3b = (const float*)d_in[18];
  float* out = (float*)d_out;
  float* ws = (float*)d_ws;

  const int B = 4096;
  float* SUM1 = ws + 0;   float* SQ1 = ws + 12;
  float* SUM2 = ws + 24;  float* SQ2 = ws + 48;
  float* SUM3 = ws + 72;  float* SQ3 = ws + 120;
  float* SUM4 = ws + 168; float* SQ4 = ws + 264;
  __half* H0  = (__half*)(ws + 1024);
  __half* W2P = H0;                         // 4320 halfs
  __half* W3P = H0 + 4320;                  // 17280
  __half* W4P = H0 + 21600;                 // 41472
  __half* R1h = H0 + 65536;                 // B*5400 halfs
  unsigned* R2P = (unsigned*)(R1h + (size_t)B * 5400);  // B*504 dwords
  unsigned* R3D = (unsigned*)R1h;                        // alias, B*360 dwords
  float*  R4  = (float*)(R2P + (size_t)B * 504);         // B*288 floats

  hipMemsetAsync(d_ws, 0, 384 * sizeof(float), stream);

  k_lift<<<B / NB1, 256, 0, stream>>>(x, w1, w2, w3, w4, W2P, W3P, W4P, R1h, SUM1, SQ1);
  k_stage2<<<(B + NB2 - 1) / NB2, 256, 0, stream>>>(R1h, W2P, SUM1, SQ1, g1, b1,
      1.0f / (float)(B * 450), R2P, SUM2, SQ2, B);
  k_stage3<<<B / NB3, 256, 0, stream>>>(R2P, W3P, SUM2, SQ2, g2, b2,
      1.0f / (float)(B * 84), R3D, SUM3, SQ3);
  k_stage4<<<B / NB4, 256, 0, stream>>>(R3D, W4P, SUM3, SQ3, g3, b3,
      1.0f / (float)(B * 15), R4, SUM4, SQ4);
  k_fc<<<B / 4, 256, 0, stream>>>(R4, SUM4, SQ4, g4, b4,
      1.0f / (float)(B * 3), f1w, f1b, f2w, f2b, f3w, f3b, out);
}